// Round 1
// baseline (1250.340 us; speedup 1.0000x reference)
//
#include <hip/hip_runtime.h>
#include <hip/hip_bf16.h>
#include <math.h>

// ExpertGroup: out = GELU_exact(x @ W1[e]^T) @ W2[e]^T
// x [16384, 2048], W1 [8, 4096, 2048], W2 [8, 2048, 4096], expert_idx scalar int.
// Both GEMMs are A[M,K] x B[N,K]^T -> C[M,N] (weights stored [out,in] = B^T layout).

typedef __bf16 bf16x8 __attribute__((ext_vector_type(8)));
typedef float floatx4 __attribute__((ext_vector_type(4)));

#define GLD16(gp, lp)                                                          \
  __builtin_amdgcn_global_load_lds(                                            \
      (__attribute__((address_space(1))) void*)(gp),                           \
      (__attribute__((address_space(3))) void*)(lp), 16, 0, 0)

__device__ __forceinline__ unsigned short f2bf(float f) {
  union { float f; unsigned int u; } v; v.f = f;
  unsigned int r = v.u + 0x7fffu + ((v.u >> 16) & 1u);   // RNE
  return (unsigned short)(r >> 16);
}

// Decide whether tensor inputs are bf16 (flag=1) or fp32 (flag=0).
// bf16 data: even ushort indices are bf16 values of ~N(0,1) -> exponent in
// [118,133] with ~99.8% probability. fp32 data: even ushorts are low mantissa
// bits -> ~6% probability. 64 samples separate the two regimes absolutely.
__global__ void sniff_kernel(const unsigned short* __restrict__ x,
                             int* __restrict__ flag) {
  int lane = threadIdx.x & 63;
  unsigned short u = x[lane * 2];
  int e = (u >> 7) & 0xFF;
  bool ok = (e >= 118) && (e <= 133);
  unsigned long long m = __ballot(ok ? 1 : 0);
  if (lane == 0) flag[0] = (__popcll(m) > 32) ? 1 : 0;
}

// fp32 -> bf16 convert (no-op when inputs are already bf16).
// idxp != nullptr selects one expert slice of a [8, ...] weight tensor.
__global__ void cvt_kernel(const float* __restrict__ in,
                           unsigned short* __restrict__ out,
                           const int* __restrict__ idxp, long long expert_stride,
                           const int* __restrict__ flagp) {
  if (flagp[0]) return;  // inputs already bf16; GEMMs read them directly
  long long base = idxp ? (long long)idxp[0] * expert_stride : 0;
  long long i = ((long long)blockIdx.x * blockDim.x + threadIdx.x) * 4;
  float4 v = *(const float4*)(in + base + i);
  ushort4 o;
  o.x = f2bf(v.x); o.y = f2bf(v.y); o.z = f2bf(v.z); o.w = f2bf(v.w);
  *(ushort4*)(out + i) = o;
}

// m97-structure GEMM: C[M,N] = A[M,K] * B[N,K]^T, bf16 in, fp32 accum.
// 128x128 tile, BK=32, 256 threads (4 waves, 2x2), 4x4 mfma_f32_16x16x32_bf16
// per wave. LDS staged with global_load_lds width=16 in wave-linear chunk
// order (dest = base + lane*16 constraint). GELU=true: exact-erf GELU + bf16
// store (h). GELU=false: plain store, dtype selected by flag (bf16/fp32).
template <bool GELU, int N, int K>
__global__ __launch_bounds__(256) void gemm_bt(
    const unsigned short* __restrict__ Aws,   // pre-converted A (fp32 mode)
    const unsigned short* __restrict__ Araw,  // raw bf16 A (bf16 mode)
    const unsigned short* __restrict__ Bws,   // pre-converted expert slice
    const unsigned short* __restrict__ Braw,  // raw bf16 weights (all experts)
    const int* __restrict__ idxp, long long expert_stride,
    void* __restrict__ Cv, const int* __restrict__ flagp) {
  const int flag = flagp[0];
  const unsigned short* __restrict__ A = flag ? Araw : Aws;
  const unsigned short* __restrict__ B =
      flag ? (Braw + (long long)idxp[0] * expert_stride) : Bws;

  __shared__ __align__(16) unsigned short As[128 * 32];
  __shared__ __align__(16) unsigned short Bs[128 * 32];

  const int tid  = threadIdx.x;
  const int lane = tid & 63;
  const int wave = tid >> 6;
  const int m0 = blockIdx.y * 128;
  const int n0 = blockIdx.x * 128;
  const int wm = (wave >> 1) * 64;   // wave's M offset in tile
  const int wn = (wave & 1) * 64;    // wave's N offset in tile
  const int lrow = lane & 15;
  const int quad = lane >> 4;

  // staging: thread t loads 16B chunks t and t+256 of each 8KB tile
  const int srow = tid >> 2;         // 0..63
  const int scol = (tid & 3) * 8;
  const unsigned short* ga0 = A + (long long)(m0 + srow) * K + scol;
  const unsigned short* ga1 = ga0 + 64LL * K;
  const unsigned short* gb0 = B + (long long)(n0 + srow) * K + scol;
  const unsigned short* gb1 = gb0 + 64LL * K;
  unsigned short* la0 = &As[tid * 8];
  unsigned short* la1 = &As[tid * 8 + 2048];
  unsigned short* lb0 = &Bs[tid * 8];
  unsigned short* lb1 = &Bs[tid * 8 + 2048];

  floatx4 acc[4][4] = {};

  for (int k0 = 0; k0 < K; k0 += 32) {
    GLD16(ga0, la0);
    GLD16(ga1, la1);
    GLD16(gb0, lb0);
    GLD16(gb1, lb1);
    __syncthreads();  // compiler drains vmcnt before s_barrier

    bf16x8 af[4], bfr[4];
#pragma unroll
    for (int i = 0; i < 4; ++i) {
      // A-frag: A[m = lane&15][k = quad*8 + j]; B-frag symmetric on [N,K]
      af[i]  = *(const bf16x8*)(&As[(wm + i * 16 + lrow) * 32 + quad * 8]);
      bfr[i] = *(const bf16x8*)(&Bs[(wn + i * 16 + lrow) * 32 + quad * 8]);
    }
#pragma unroll
    for (int i = 0; i < 4; ++i)
#pragma unroll
      for (int j = 0; j < 4; ++j)
        acc[i][j] = __builtin_amdgcn_mfma_f32_16x16x32_bf16(af[i], bfr[j],
                                                            acc[i][j], 0, 0, 0);
    __syncthreads();
    ga0 += 32; ga1 += 32; gb0 += 32; gb1 += 32;
  }

  // C/D layout (m89/m91-verified): col = lane&15, row = quad*4 + reg
  if (GELU) {
    unsigned short* Cp = (unsigned short*)Cv;
#pragma unroll
    for (int i = 0; i < 4; ++i) {
      const int rb = m0 + wm + i * 16 + quad * 4;
#pragma unroll
      for (int j = 0; j < 4; ++j) {
        const int col = n0 + wn + j * 16 + lrow;
#pragma unroll
        for (int r = 0; r < 4; ++r) {
          float v = acc[i][j][r];
          v = 0.5f * v * (1.0f + erff(v * 0.70710678118654752f));
          Cp[(long long)(rb + r) * N + col] = f2bf(v);
        }
      }
    }
  } else if (flag) {  // bf16 output
    unsigned short* Cp = (unsigned short*)Cv;
#pragma unroll
    for (int i = 0; i < 4; ++i) {
      const int rb = m0 + wm + i * 16 + quad * 4;
#pragma unroll
      for (int j = 0; j < 4; ++j) {
        const int col = n0 + wn + j * 16 + lrow;
#pragma unroll
        for (int r = 0; r < 4; ++r)
          Cp[(long long)(rb + r) * N + col] = f2bf(acc[i][j][r]);
      }
    }
  } else {  // fp32 output
    float* Cp = (float*)Cv;
#pragma unroll
    for (int i = 0; i < 4; ++i) {
      const int rb = m0 + wm + i * 16 + quad * 4;
#pragma unroll
      for (int j = 0; j < 4; ++j) {
        const int col = n0 + wn + j * 16 + lrow;
#pragma unroll
        for (int r = 0; r < 4; ++r)
          Cp[(long long)(rb + r) * N + col] = acc[i][j][r];
      }
    }
  }
}

extern "C" void kernel_launch(void* const* d_in, const int* in_sizes, int n_in,
                              void* d_out, int out_size, void* d_ws,
                              size_t ws_size, hipStream_t stream) {
  const int* idxp = (const int*)d_in[0];
  const void* x  = d_in[1];   // [16384, 2048]
  const void* W1 = d_in[2];   // [8, 4096, 2048]
  const void* W2 = d_in[3];   // [8, 2048, 4096]

  // ws layout (bf16-mode only touches the first ~128 MiB):
  //   [0,256)        : dtype flag
  //   [256, +128MiB) : h bf16 [16384, 4096]
  //   then x_bf16 (64 MiB), w1_bf16 (16 MiB), w2_bf16 (16 MiB)  (fp32 mode)
  char* ws = (char*)d_ws;
  int* flag = (int*)ws;
  unsigned short* h   = (unsigned short*)(ws + 256);
  unsigned short* xb  = (unsigned short*)(ws + 256 + 134217728LL);
  unsigned short* w1b = xb + 33554432LL;
  unsigned short* w2b = w1b + 8388608LL;

  sniff_kernel<<<dim3(1), dim3(64), 0, stream>>>((const unsigned short*)x, flag);

  // fp32->bf16 converts (early-out when inputs are already bf16)
  cvt_kernel<<<dim3(32768), dim3(256), 0, stream>>>((const float*)x, xb,
                                                    nullptr, 0, flag);
  cvt_kernel<<<dim3(8192), dim3(256), 0, stream>>>((const float*)W1, w1b,
                                                   idxp, 8388608LL, flag);
  cvt_kernel<<<dim3(8192), dim3(256), 0, stream>>>((const float*)W2, w2b,
                                                   idxp, 8388608LL, flag);

  // GEMM1: h = GELU(x @ W1[e]^T)   M=16384, N=4096, K=2048
  gemm_bt<true, 4096, 2048><<<dim3(32, 128), dim3(256), 0, stream>>>(
      xb, (const unsigned short*)x, w1b, (const unsigned short*)W1, idxp,
      8388608LL, h, flag);

  // GEMM2: out = h @ W2[e]^T       M=16384, N=2048, K=4096
  gemm_bt<false, 2048, 4096><<<dim3(16, 128), dim3(256), 0, stream>>>(
      h, h, w2b, (const unsigned short*)W2, idxp, 8388608LL, d_out, flag);
}